// Round 7
// baseline (1627.436 us; speedup 1.0000x reference)
//
#include <hip/hip_runtime.h>

// RoIAlign matching jax.image.scale_and_translate(method="linear", antialias=True)
// feature_map: [512][512][64] f32, boxes: [512][4] f32 (cx,cy,w,h), out: [512][32][32][64] f32
// Wave-private separable resize: 1-wave blocks (8ox x 16ch x 16oy), per-wave LDS
// double-buffer, NO main-loop barriers — self-paced vmcnt(0) pipeline per wave.

#define H_IN 512
#define W_IN 512
#define CH   64
#define NB   512
#define OW   32
#define WSTRIDE 33    // weights per (box,dim,o) in the global table
#define WXS     40    // padded x-weight stride in LDS (zeros at [cnt,40))
#define TAPS_MAX 33
#define COLS_H  156   // 8-ox union: span <= 7*16+33 = 145, +8 chunk pad, +slack
#define COLS_CL 146   // clamp for cux

// ---------------------------------------------------------------------------
// Kernel 1: per (box, dim, o) tap table (unchanged — verified correct R1-R5).
// ---------------------------------------------------------------------------
__global__ __launch_bounds__(256) void roi_weights(const float* __restrict__ boxes,
                                                   float* __restrict__ wTab,
                                                   int* __restrict__ meta) {
    int tid = blockIdx.x * blockDim.x + threadIdx.x;
    if (tid >= NB * 2 * 32) return;
    int o   = tid & 31;
    int dim = (tid >> 5) & 1;   // 0 = y, 1 = x
    int b   = tid >> 6;

    float cx = boxes[b * 4 + 0];
    float cy = boxes[b * 4 + 1];
    float bw = boxes[b * 4 + 2];
    float bh = boxes[b * 4 + 3];
    float cc = dim ? cx : cy;
    float sz = dim ? bw : bh;
    float lo = cc - sz * 0.5f;        // x0/y0 use PRE-clamp size (matches ref)
    sz = fmaxf(sz, 1e-6f);

    float scale = (float)OW / (sz * (float)W_IN);
    float inv   = 1.0f / scale;
    float trans = (-lo * (float)OW) / sz;
    float s     = ((float)o + 0.5f) * inv - trans * inv - 0.5f;
    float ks    = fmaxf(inv, 1.0f);

    int i_lo = max((int)ceilf(s - ks), 0);
    int i_hi = min((int)floorf(s + ks), W_IN - 1);
    int cnt  = i_hi - i_lo + 1;
    if (cnt < 0) cnt = 0;
    if (cnt > TAPS_MAX) cnt = TAPS_MAX;

    float sum = 0.0f;
    for (int k = 0; k < cnt; ++k) {
        float x = fabsf(s - (float)(i_lo + k)) / ks;
        sum += fmaxf(0.0f, 1.0f - x);
    }
    bool ok = (sum > 1.1920929e-4f) && (s >= -0.5f) && (s <= (float)W_IN - 0.5f);

    float* wout = wTab + ((size_t)(dim * NB + b) * 32 + o) * WSTRIDE;
    for (int k = 0; k < TAPS_MAX; ++k) {
        float w = 0.0f;
        if (ok && k < cnt) {
            float x = fabsf(s - (float)(i_lo + k)) / ks;
            w = fmaxf(0.0f, 1.0f - x) / sum;
        }
        wout[k] = w;
    }
    int* m = meta + ((size_t)(dim * NB + b) * 32 + o) * 2;
    m[0] = i_lo;
    m[1] = ok ? cnt : 0;
}

// direct global->LDS, 16B per lane; LDS dest = wave-uniform base + laneid*16
__device__ __forceinline__ void gload16(const float* src, float* ldsDst) {
    __builtin_amdgcn_global_load_lds((const __attribute__((address_space(1))) void*)src,
                                     (__attribute__((address_space(3))) void*)ldsDst, 16, 0, 0);
}

// ---------------------------------------------------------------------------
// Kernel 2: wave-private separable RoI resize. 1 wave per block.
// bid: box = ((bid>>8)<<3)|(bid&7) -> a box's 32 sub-blocks on one XCD.
// sub = (bid>>3)&31: oxq = sub&3 (8 ox), chq = (sub>>2)&3 (16 ch), oyh = sub>>4 (16 oy).
// Per row: issue next-row global_load_lds into other buffer, x-pass chunk-8
// from current buffer, y-accumulate, s_waitcnt vmcnt(0) (no barrier), swap.
// ---------------------------------------------------------------------------
__global__ __launch_bounds__(64) void roi_wave(const float* __restrict__ fm,
                                               const float* __restrict__ wTab,
                                               const int* __restrict__ meta,
                                               float* __restrict__ out) {
    __shared__ float sBuf[2][COLS_H * 16];   // 19.5 KB, [col][16ch] linear per buffer
    __shared__ float sWx[8 * WXS];           // 1.25 KB, zero-padded taps
    __shared__ float sWy[16 * WSTRIDE];      // 2.06 KB
    __shared__ int   sMx[16];                // (ix0, cntx) per local ox
    __shared__ int   sMyLC[16];              // i_lo | cnt<<16 per oy
    __shared__ int   sU[4];                  // u0, cu, xu0, cux

    int bid = blockIdx.x;
    int box = ((bid >> 8) << 3) | (bid & 7);
    int sub = (bid >> 3) & 31;
    int ox0 = (sub & 3) * 8;
    int ch0 = ((sub >> 2) & 3) * 16;
    int oy0 = (sub >> 4) * 16;
    int t   = threadIdx.x;

    const float* wxsrc = wTab + ((size_t)(NB + box) * 32 + ox0) * WSTRIDE;
    for (int i = t; i < 8 * WXS; i += 64) {
        int o = i / WXS, k = i - o * WXS;
        sWx[i] = (k < WSTRIDE) ? wxsrc[o * WSTRIDE + k] : 0.0f;
    }
    const float* wysrc = wTab + ((size_t)box * 32 + oy0) * WSTRIDE;
    for (int i = t; i < 16 * WSTRIDE; i += 64) sWy[i] = wysrc[i];
    if (t < 16) sMx[t] = meta[((size_t)(NB + box) * 32 + ox0) * 2 + t];
    if (t >= 16 && t < 32) {
        int k  = t - 16;
        int lo = meta[((size_t)box * 32 + oy0 + k) * 2];
        int cn = meta[((size_t)box * 32 + oy0 + k) * 2 + 1];
        sMyLC[k] = (lo & 0xffff) | (cn << 16);
    }
    __syncthreads();
    if (t == 0) {
        int lo = 0x7fffffff, hi = -1;
        for (int k = 0; k < 16; ++k) {
            int lc = sMyLC[k], c = lc >> 16;
            if (c > 0) { int l = lc & 0xffff; lo = min(lo, l); hi = max(hi, l + c); }
        }
        sU[0] = (hi > lo) ? lo : 0;
        sU[1] = (hi > lo) ? (hi - lo) : 0;
        int xlo = 0x7fffffff, xhi = -1;
        for (int k = 0; k < 8; ++k) {
            int c = sMx[2 * k + 1];
            if (c > 0) { int l = sMx[2 * k]; xlo = min(xlo, l); xhi = max(xhi, l + c); }
        }
        sU[2] = (xhi > xlo) ? xlo : 0;
        int cux = (xhi > xlo) ? (xhi - xlo) : 0;
        sU[3] = (cux > COLS_CL) ? COLS_CL : cux;
    }
    __syncthreads();
    int u0 = sU[0], cu = sU[1], xu0 = sU[2], cux = sU[3];

    int ox = t >> 3, cp = t & 7;
    int ix0rel = max(sMx[2 * ox] - xu0, 0);
    int cntx   = sMx[2 * ox + 1];
    int nch    = (cntx + 7) >> 3;

    int myLC[16];
    #pragma unroll
    for (int k = 0; k < 16; ++k) myLC[k] = sMyLC[k];

    float accA[16], accB[16];
    #pragma unroll
    for (int k = 0; k < 16; ++k) { accA[k] = 0.f; accB[k] = 0.f; }

    // zero pad cols [cux, cux+8) of both buffers (chunk-8 overread -> +0.0)
    for (int i = t; i < 2 * 8 * 16; i += 64) {
        int b = i >> 7, col = (i >> 4) & 7, ch = i & 15;
        sBuf[b][(cux + col) * 16 + ch] = 0.0f;
    }

    // per-lane staging source: col-in-group = t>>2 (16 cols/instr), ch-quad = t&3
    const float* laneSrc = fm + (size_t)(xu0 + (t >> 2)) * CH + ch0 + (t & 3) * 4;
    int laneCol = t >> 2;

    // prologue: stage row 0 into buf 0
    if (cu > 0) {
        const float* rowSrc = laneSrc + (size_t)u0 * (W_IN * CH);
        for (int c0w = 0; c0w < cux; c0w += 16) {
            if (c0w + laneCol < cux) gload16(rowSrc + c0w * CH, &sBuf[0][c0w * 16]);
        }
    }
    __syncthreads();   // one-time: pads + prologue staging drained

    int cur = 0;
    for (int r = 0; r < cu; ++r) {
        // issue stage of row r+1 into the other buffer (overlaps this row's compute)
        if (r + 1 < cu) {
            const float* rowSrc = laneSrc + (size_t)(u0 + r + 1) * (W_IN * CH);
            float* dst = &sBuf[cur ^ 1][0];
            for (int c0w = 0; c0w < cux; c0w += 16) {
                if (c0w + laneCol < cux) gload16(rowSrc + c0w * CH, dst + c0w * 16);
            }
        }

        // x-pass: chunk-8, 8 LDS b64 reads in flight, statically indexed regs
        const float* wxp = &sWx[ox * WXS];
        const float* bp  = &sBuf[cur][0] + ix0rel * 16 + cp * 2;
        float xa = 0.f, xb = 0.f;
        for (int c = 0; c < nch; ++c) {
            float2 v[8];
            #pragma unroll
            for (int k = 0; k < 8; ++k) v[k] = *(const float2*)(bp + k * 16);
            float4 w0 = *(const float4*)(wxp + c * 8);
            float4 w1 = *(const float4*)(wxp + c * 8 + 4);
            xa = fmaf(w0.x, v[0].x, xa); xb = fmaf(w0.x, v[0].y, xb);
            xa = fmaf(w0.y, v[1].x, xa); xb = fmaf(w0.y, v[1].y, xb);
            xa = fmaf(w0.z, v[2].x, xa); xb = fmaf(w0.z, v[2].y, xb);
            xa = fmaf(w0.w, v[3].x, xa); xb = fmaf(w0.w, v[3].y, xb);
            xa = fmaf(w1.x, v[4].x, xa); xb = fmaf(w1.x, v[4].y, xb);
            xa = fmaf(w1.y, v[5].x, xa); xb = fmaf(w1.y, v[5].y, xb);
            xa = fmaf(w1.z, v[6].x, xa); xb = fmaf(w1.z, v[6].y, xb);
            xa = fmaf(w1.w, v[7].x, xa); xb = fmaf(w1.w, v[7].y, xb);
            bp += 128;
        }

        // y-accumulate: statically unrolled, predicate from hoisted regs
        int iy = u0 + r;
        #pragma unroll
        for (int oy = 0; oy < 16; ++oy) {
            int lc = myLC[oy];
            int rr = iy - (lc & 0xffff);
            if ((unsigned)rr < (unsigned)(lc >> 16)) {
                float w = sWy[oy * WSTRIDE + rr];
                accA[oy] = fmaf(w, xa, accA[oy]);
                accB[oy] = fmaf(w, xb, accB[oy]);
            }
        }

        // wave-local wait: next row's staging (and this row's reads) complete.
        // No barrier — this wave is the only user of its buffers.
        asm volatile("s_waitcnt vmcnt(0)" ::: "memory");
        cur ^= 1;
    }

    // store: 16 oy x float2 per thread (zeros where no coverage — matches ref)
    #pragma unroll
    for (int oy = 0; oy < 16; ++oy) {
        float* op = out + (((size_t)box * 32 + oy0 + oy) * 32 + ox0 + ox) * CH + ch0 + cp * 2;
        *(float2*)op = make_float2(accA[oy], accB[oy]);
    }
}

extern "C" void kernel_launch(void* const* d_in, const int* in_sizes, int n_in,
                              void* d_out, int out_size, void* d_ws, size_t ws_size,
                              hipStream_t stream) {
    const float* fm    = (const float*)d_in[0];
    const float* boxes = (const float*)d_in[1];
    // d_in[2] = output_width (==32), hardcoded.

    float* wTab = (float*)d_ws;                                   // 2*512*32*33 f32 = 4.33 MB
    int*   meta = (int*)((char*)d_ws + (size_t)2 * NB * 32 * WSTRIDE * sizeof(float)); // 512 KB

    roi_weights<<<(NB * 2 * 32 + 255) / 256, 256, 0, stream>>>(boxes, wTab, meta);
    roi_wave<<<NB * 32, 64, 0, stream>>>(fm, wTab, meta, (float*)d_out);
}